// Round 1
// baseline (346.965 us; speedup 1.0000x reference)
//
#include <hip/hip_runtime.h>
#include <math.h>

typedef unsigned short u16;
typedef __bf16 bf16x8 __attribute__((ext_vector_type(8)));
typedef float f32x4 __attribute__((ext_vector_type(4)));
typedef unsigned short u16x8 __attribute__((ext_vector_type(8)));

#define S_LEN 2048
#define BATCH 2
#define HID 512
#define NHEAD 8
#define DHEAD 64
#define DFF 2048
#define ROWS (BATCH * S_LEN)  // 4096

static __device__ __forceinline__ u16 f2bf(float f) {
  unsigned int u = __builtin_bit_cast(unsigned int, f);
  u += 0x7fffu + ((u >> 16) & 1u);
  return (u16)(u >> 16);
}

// ---------------- mask dtype detection + canonicalization ----------------
// adj_mask is a bool array; harness storage could be int32, f32, or 1-byte.
// Classify by reading the first 1024 words: random 0/1 data makes each case
// unambiguous (byte storage can't produce 1024 ints all in {0,1}; f32 1.0 is
// 0x3f800000). Deterministic: same input -> same flag.
__global__ void detect_mask_kernel(const unsigned int* __restrict__ m,
                                   int* __restrict__ flag) {
  int lane = threadIdx.x & 63;
  int notint = 0, notf32 = 0;
  for (int i = lane; i < 1024; i += 64) {
    unsigned int v = m[i];
    if (v > 1u) notint = 1;
    if (v != 0u && v != 0x3f800000u) notf32 = 1;
  }
  unsigned long long bi = __ballot(notint);
  unsigned long long bf = __ballot(notf32);
  if (lane == 0) *flag = (bi == 0ull) ? 1 : ((bf == 0ull) ? 2 : 0);
}

__global__ void mask_canon_kernel(const void* __restrict__ m,
                                  const int* __restrict__ flagp,
                                  unsigned char* __restrict__ out, int n) {
  int flag = *flagp;
  int i = blockIdx.x * blockDim.x + threadIdx.x;
  int stride = gridDim.x * blockDim.x;
  if (flag == 1) {
    const int* p = (const int*)m;
    for (; i < n; i += stride) out[i] = (p[i] != 0);
  } else if (flag == 2) {
    const float* p = (const float*)m;
    for (; i < n; i += stride) out[i] = (p[i] != 0.f);
  } else {
    const unsigned char* p = (const unsigned char*)m;
    for (; i < n; i += stride) out[i] = (p[i] != 0);
  }
}

// ---------------- f32 -> bf16 weight conversion ----------------
__global__ void cvt_kernel(const float* __restrict__ s, u16* __restrict__ d) {
  int i = (blockIdx.x * 256 + threadIdx.x) * 8;
  float4 a = *(const float4*)(s + i);
  float4 b = *(const float4*)(s + i + 4);
  u16x8 o;
  o[0] = f2bf(a.x); o[1] = f2bf(a.y); o[2] = f2bf(a.z); o[3] = f2bf(a.w);
  o[4] = f2bf(b.x); o[5] = f2bf(b.y); o[6] = f2bf(b.z); o[7] = f2bf(b.w);
  *(u16x8*)(d + i) = o;
}

// ---------------- LayerNorm (f32 in, bf16 out), one wave per row ----------------
__global__ __launch_bounds__(256) void ln_kernel(const float* __restrict__ x,
                                                 const float* __restrict__ g,
                                                 const float* __restrict__ b,
                                                 u16* __restrict__ o) {
  int wid = threadIdx.x >> 6, lane = threadIdx.x & 63;
  long row = (long)blockIdx.x * 4 + wid;
  const float* xr = x + row * HID;
  float4 v0 = *(const float4*)(xr + lane * 8);
  float4 v1 = *(const float4*)(xr + lane * 8 + 4);
  float fr[8] = {v0.x, v0.y, v0.z, v0.w, v1.x, v1.y, v1.z, v1.w};
  float s = 0.f, q = 0.f;
#pragma unroll
  for (int j = 0; j < 8; ++j) { s += fr[j]; q += fr[j] * fr[j]; }
#pragma unroll
  for (int mby = 1; mby < 64; mby <<= 1) {
    s += __shfl_xor(s, mby);
    q += __shfl_xor(q, mby);
  }
  float mean = s * (1.f / HID);
  float var = q * (1.f / HID) - mean * mean;
  float rs = rsqrtf(var + 1e-5f);
  u16x8 ov;
#pragma unroll
  for (int j = 0; j < 8; ++j) {
    int c = lane * 8 + j;
    ov[j] = f2bf((fr[j] - mean) * rs * g[c] + b[c]);
  }
  *(u16x8*)(o + row * HID + lane * 8) = ov;
}

// ---------------- generic bf16 MFMA GEMM: C = A[MxK] * B[KxN] (+bias, epi) ----------------
// EPI 0: out bf16 = acc + bias
// EPI 1: out f32  = resid + acc + bias
// EPI 2: out bf16 = gelu(acc + bias)   (exact erf gelu)
template <int EPI>
__global__ __launch_bounds__(256) void gemm_kernel(
    const u16* __restrict__ A, const u16* __restrict__ Bw,
    const float* __restrict__ bias, const float* __restrict__ resid,
    void* __restrict__ outv, int M, int N, int K) {
  __shared__ alignas(16) u16 sA[64][40];  // [m][k], +8 pad
  __shared__ alignas(16) u16 sB[64][40];  // transposed: [n][k], +8 pad
  int tid = threadIdx.x;
  int wid = tid >> 6, lane = tid & 63;
  int wm = wid >> 1, wn = wid & 1;
  int grp = lane >> 4, l16 = lane & 15;
  int m0 = blockIdx.y * 64, n0 = blockIdx.x * 64;
  f32x4 z = {0.f, 0.f, 0.f, 0.f};
  f32x4 acc00 = z, acc01 = z, acc10 = z, acc11 = z;
  int ar = tid >> 2, ac = (tid & 3) * 8;
  int bk = tid >> 3, bn8 = (tid & 7) * 8;
  for (int k0 = 0; k0 < K; k0 += 32) {
    uint4 av = *(const uint4*)(A + (long)(m0 + ar) * K + k0 + ac);
    u16x8 wv = *(const u16x8*)(Bw + (long)(k0 + bk) * N + n0 + bn8);
    *(uint4*)&sA[ar][ac] = av;
#pragma unroll
    for (int i = 0; i < 8; ++i) sB[bn8 + i][bk] = wv[i];
    __syncthreads();
    bf16x8 a0 = *(const bf16x8*)&sA[wm * 32 + l16][grp * 8];
    bf16x8 a1 = *(const bf16x8*)&sA[wm * 32 + 16 + l16][grp * 8];
    bf16x8 b0 = *(const bf16x8*)&sB[wn * 32 + l16][grp * 8];
    bf16x8 b1 = *(const bf16x8*)&sB[wn * 32 + 16 + l16][grp * 8];
    acc00 = __builtin_amdgcn_mfma_f32_16x16x32_bf16(a0, b0, acc00, 0, 0, 0);
    acc01 = __builtin_amdgcn_mfma_f32_16x16x32_bf16(a0, b1, acc01, 0, 0, 0);
    acc10 = __builtin_amdgcn_mfma_f32_16x16x32_bf16(a1, b0, acc10, 0, 0, 0);
    acc11 = __builtin_amdgcn_mfma_f32_16x16x32_bf16(a1, b1, acc11, 0, 0, 0);
    __syncthreads();
  }
#pragma unroll
  for (int am = 0; am < 2; ++am) {
#pragma unroll
    for (int bn = 0; bn < 2; ++bn) {
      f32x4 acc = (am == 0) ? (bn == 0 ? acc00 : acc01) : (bn == 0 ? acc10 : acc11);
#pragma unroll
      for (int r = 0; r < 4; ++r) {
        long gr = m0 + wm * 32 + am * 16 + grp * 4 + r;
        int gc = n0 + wn * 32 + bn * 16 + l16;
        float v = acc[r] + bias[gc];
        long off = gr * N + gc;
        if constexpr (EPI == 0) {
          ((u16*)outv)[off] = f2bf(v);
        } else if constexpr (EPI == 1) {
          ((float*)outv)[off] = resid[off] + v;
        } else {
          ((u16*)outv)[off] = f2bf(0.5f * v * (1.f + erff(v * 0.70710678118f)));
        }
      }
    }
  }
}

// ---------------- flash attention, bf16 MFMA, online softmax ----------------
// grid: (S/64, NHEAD, BATCH); 4 waves/block, each wave owns 16 q-rows.
__global__ __launch_bounds__(256) void attn_kernel(
    const u16* __restrict__ qg, const u16* __restrict__ kg,
    const u16* __restrict__ vg, const unsigned char* __restrict__ mk,
    u16* __restrict__ og) {
  __shared__ alignas(16) u16 sP[4][16][88];  // per-wave P tile, padded stride
  int wid = threadIdx.x >> 6, lane = threadIdx.x & 63;
  int grp = lane >> 4, l16 = lane & 15;
  int h = blockIdx.y, b = blockIdx.z;
  int q0 = blockIdx.x * 64 + wid * 16;  // within-batch q row base for this wave
  long qrow = (long)b * S_LEN + q0 + l16;
  const u16* qp = qg + qrow * HID + h * DHEAD + grp * 8;
  bf16x8 qf0 = *(const bf16x8*)qp;
  bf16x8 qf1 = *(const bf16x8*)(qp + 32);
  f32x4 z = {0.f, 0.f, 0.f, 0.f};
  f32x4 oa[4] = {z, z, z, z};
  float mrow[4] = {-INFINITY, -INFINITY, -INFINITY, -INFINITY};
  float lrow[4] = {0.f, 0.f, 0.f, 0.f};
  const unsigned char* mbase = mk + (long)b * S_LEN * S_LEN;

  for (int kv0 = 0; kv0 < S_LEN; kv0 += 64) {
    // S = Q K^T   (16 q-rows x 64 kv-cols per wave)
    f32x4 sreg[4];
#pragma unroll
    for (int nb = 0; nb < 4; ++nb) {
      long krow = (long)b * S_LEN + kv0 + nb * 16 + l16;
      const u16* kp = kg + krow * HID + h * DHEAD + grp * 8;
      bf16x8 kf0 = *(const bf16x8*)kp;
      bf16x8 kf1 = *(const bf16x8*)(kp + 32);
      f32x4 s = z;
      s = __builtin_amdgcn_mfma_f32_16x16x32_bf16(qf0, kf0, s, 0, 0, 0);
      s = __builtin_amdgcn_mfma_f32_16x16x32_bf16(qf1, kf1, s, 0, 0, 0);
      sreg[nb] = s;
    }
    // mask + scale + online softmax (rows live on (grp, r); 16 lanes = 16 cols)
#pragma unroll
    for (int r = 0; r < 4; ++r) {
      const unsigned char* mrowp = mbase + (long)(q0 + grp * 4 + r) * S_LEN + kv0;
      float sv[4];
      float mx = -INFINITY;
#pragma unroll
      for (int nb = 0; nb < 4; ++nb) {
        int mv = mrowp[nb * 16 + l16];
        sv[nb] = mv ? sreg[nb][r] * 0.125f : -1e9f;
        mx = fmaxf(mx, sv[nb]);
      }
      mx = fmaxf(mx, __shfl_xor(mx, 1));
      mx = fmaxf(mx, __shfl_xor(mx, 2));
      mx = fmaxf(mx, __shfl_xor(mx, 4));
      mx = fmaxf(mx, __shfl_xor(mx, 8));
      float mnew = fmaxf(mrow[r], mx);
      float scale = __expf(mrow[r] - mnew);  // exp(-inf - finite) = 0
      float rsum = 0.f;
#pragma unroll
      for (int nb = 0; nb < 4; ++nb) {
        float p = __expf(sv[nb] - mnew);
        rsum += p;
        sP[wid][grp * 4 + r][nb * 16 + l16] = f2bf(p);
      }
      rsum += __shfl_xor(rsum, 1);
      rsum += __shfl_xor(rsum, 2);
      rsum += __shfl_xor(rsum, 4);
      rsum += __shfl_xor(rsum, 8);
      mrow[r] = mnew;
      lrow[r] = lrow[r] * scale + rsum;
#pragma unroll
      for (int db = 0; db < 4; ++db) oa[db][r] *= scale;
    }
    __syncthreads();
    // O += P V
#pragma unroll
    for (int ks = 0; ks < 2; ++ks) {
      bf16x8 pa = *(const bf16x8*)&sP[wid][l16][ks * 32 + grp * 8];
#pragma unroll
      for (int db = 0; db < 4; ++db) {
        u16x8 tv;
#pragma unroll
        for (int j = 0; j < 8; ++j) {
          long vrow = (long)b * S_LEN + kv0 + ks * 32 + grp * 8 + j;
          tv[j] = vg[vrow * HID + h * DHEAD + db * 16 + l16];
        }
        bf16x8 vf = __builtin_bit_cast(bf16x8, tv);
        oa[db] = __builtin_amdgcn_mfma_f32_16x16x32_bf16(pa, vf, oa[db], 0, 0, 0);
      }
    }
    __syncthreads();
  }
#pragma unroll
  for (int r = 0; r < 4; ++r) {
    float inv = 1.f / lrow[r];
    long orow = (long)b * S_LEN + q0 + grp * 4 + r;
#pragma unroll
    for (int db = 0; db < 4; ++db) {
      og[orow * HID + h * DHEAD + db * 16 + l16] = f2bf(oa[db][r] * inv);
    }
  }
}

// ---------------- launch ----------------
extern "C" void kernel_launch(void* const* d_in, const int* in_sizes, int n_in,
                              void* d_out, int out_size, void* d_ws,
                              size_t ws_size, hipStream_t stream) {
  const float* x = (const float*)d_in[0];
  const void* mask = d_in[1];
  const float* ln1g = (const float*)d_in[2];
  const float* ln1b = (const float*)d_in[3];
  const float* ln2g = (const float*)d_in[4];
  const float* ln2b = (const float*)d_in[5];
  const float* Wq = (const float*)d_in[6];
  const float* bq = (const float*)d_in[7];
  const float* Wk = (const float*)d_in[8];
  const float* bk = (const float*)d_in[9];
  const float* Wv = (const float*)d_in[10];
  const float* bv = (const float*)d_in[11];
  const float* Wo = (const float*)d_in[12];
  const float* bo = (const float*)d_in[13];
  const float* W1 = (const float*)d_in[14];
  const float* b1 = (const float*)d_in[15];
  const float* W2 = (const float*)d_in[16];
  const float* b2 = (const float*)d_in[17];

  char* w = (char*)d_ws;
  int* flag = (int*)w;
  char* base = w + 256;
  // Buffer plan (with reuse):
  //  [0 .. 16.77M)  : mcan(8.39M) | nx(4.19M) | qb(4.19M)  -> later hb(16.77M)
  //  then kb(4.19M) -> later nx2; vb(4.19M); ao(4.19M); x2(8.39M); bf16 weights(6.29M)
  unsigned char* mcan = (unsigned char*)base;
  u16* nx = (u16*)(base + 8388608);
  u16* qb = (u16*)(base + 8388608 + 4194304);
  u16* hb = (u16*)base;  // reuses mcan+nx+qb after attention
  u16* kb = (u16*)(base + 16777216);
  u16* nx2 = kb;  // reuses kb after attention
  u16* vb = (u16*)(base + 16777216 + 4194304);
  u16* ao = (u16*)(base + 16777216 + 2 * 4194304);
  float* x2 = (float*)(base + 16777216 + 3 * 4194304);
  u16* wqb = (u16*)(base + 16777216 + 3 * 4194304 + 8388608);
  u16* wkb = wqb + 512 * 512;
  u16* wvb = wkb + 512 * 512;
  u16* wob = wvb + 512 * 512;
  u16* w1b = wob + 512 * 512;
  u16* w2b = w1b + 512 * 2048;

  detect_mask_kernel<<<1, 64, 0, stream>>>((const unsigned int*)mask, flag);
  mask_canon_kernel<<<4096, 256, 0, stream>>>(mask, flag, mcan,
                                              BATCH * S_LEN * S_LEN);
  cvt_kernel<<<128, 256, 0, stream>>>(Wq, wqb);
  cvt_kernel<<<128, 256, 0, stream>>>(Wk, wkb);
  cvt_kernel<<<128, 256, 0, stream>>>(Wv, wvb);
  cvt_kernel<<<128, 256, 0, stream>>>(Wo, wob);
  cvt_kernel<<<512, 256, 0, stream>>>(W1, w1b);
  cvt_kernel<<<512, 256, 0, stream>>>(W2, w2b);
  ln_kernel<<<1024, 256, 0, stream>>>(x, ln1g, ln1b, nx);
  gemm_kernel<0><<<dim3(8, 64), 256, 0, stream>>>(nx, wqb, bq, nullptr, qb,
                                                  ROWS, HID, HID);
  gemm_kernel<0><<<dim3(8, 64), 256, 0, stream>>>(nx, wkb, bk, nullptr, kb,
                                                  ROWS, HID, HID);
  gemm_kernel<0><<<dim3(8, 64), 256, 0, stream>>>(nx, wvb, bv, nullptr, vb,
                                                  ROWS, HID, HID);
  attn_kernel<<<dim3(32, 8, 2), 256, 0, stream>>>(qb, kb, vb, mcan, ao);
  gemm_kernel<1><<<dim3(8, 64), 256, 0, stream>>>(ao, wob, bo, x, x2, ROWS,
                                                  HID, HID);
  ln_kernel<<<1024, 256, 0, stream>>>(x2, ln2g, ln2b, nx2);
  gemm_kernel<2><<<dim3(32, 64), 256, 0, stream>>>(nx2, w1b, b1, nullptr, hb,
                                                   ROWS, DFF, HID);
  gemm_kernel<1><<<dim3(8, 64), 256, 0, stream>>>(hb, w2b, b2, x2,
                                                  (float*)d_out, ROWS, HID, DFF);
}

// Round 2
// 263.110 us; speedup vs baseline: 1.3187x; 1.3187x over previous
//
#include <hip/hip_runtime.h>
#include <math.h>

typedef unsigned short u16;
typedef __bf16 bf16x8 __attribute__((ext_vector_type(8)));
typedef float f32x4 __attribute__((ext_vector_type(4)));
typedef unsigned short u16x8 __attribute__((ext_vector_type(8)));
typedef unsigned short u16x4 __attribute__((ext_vector_type(4)));

#define S_LEN 2048
#define BATCH 2
#define HID 512
#define NHEAD 8
#define DHEAD 64
#define DFF 2048
#define ROWS (BATCH * S_LEN)  // 4096

static __device__ __forceinline__ u16 f2bf(float f) {
  unsigned int u = __builtin_bit_cast(unsigned int, f);
  u += 0x7fffu + ((u >> 16) & 1u);
  return (u16)(u >> 16);
}

// async global->LDS, 16B per lane; lds dest must be wave-uniform base.
static __device__ __forceinline__ void gl16(const void* g, void* l) {
  __builtin_amdgcn_global_load_lds(
      (const __attribute__((address_space(1))) void*)g,
      (__attribute__((address_space(3))) void*)l, 16, 0, 0);
}

// ---------------- mask dtype detection + canonicalization ----------------
__global__ void detect_mask_kernel(const unsigned int* __restrict__ m,
                                   int* __restrict__ flag) {
  int lane = threadIdx.x & 63;
  int notint = 0, notf32 = 0;
  for (int i = lane; i < 1024; i += 64) {
    unsigned int v = m[i];
    if (v > 1u) notint = 1;
    if (v != 0u && v != 0x3f800000u) notf32 = 1;
  }
  unsigned long long bi = __ballot(notint);
  unsigned long long bf = __ballot(notf32);
  if (lane == 0) *flag = (bi == 0ull) ? 1 : ((bf == 0ull) ? 2 : 0);
}

__global__ void mask_canon_kernel(const void* __restrict__ m,
                                  const int* __restrict__ flagp,
                                  unsigned char* __restrict__ out, int n) {
  int flag = *flagp;
  int i = blockIdx.x * blockDim.x + threadIdx.x;
  int stride = gridDim.x * blockDim.x;
  if (flag == 1) {
    const int* p = (const int*)m;
    for (; i < n; i += stride) out[i] = (p[i] != 0);
  } else if (flag == 2) {
    const float* p = (const float*)m;
    for (; i < n; i += stride) out[i] = (p[i] != 0.f);
  } else {
    const unsigned char* p = (const unsigned char*)m;
    for (; i < n; i += stride) out[i] = (p[i] != 0);
  }
}

// ---------------- f32 W[K][N] -> bf16 WT[N][K] tiled transpose-convert ----
__global__ __launch_bounds__(256) void cvt_t_kernel(const float* __restrict__ W,
                                                    u16* __restrict__ WT,
                                                    int K, int N) {
  __shared__ u16 sT[64][80];
  int tid = threadIdx.x;
  int r = tid >> 2, c0 = (tid & 3) * 16;
  int k0 = blockIdx.y * 64, n0 = blockIdx.x * 64;
  const float* src = W + (size_t)(k0 + r) * N + n0 + c0;
  u16x8 a, b;
#pragma unroll
  for (int j = 0; j < 8; ++j) a[j] = f2bf(src[j]);
#pragma unroll
  for (int j = 0; j < 8; ++j) b[j] = f2bf(src[8 + j]);
  *(u16x8*)&sT[r][c0] = a;
  *(u16x8*)&sT[r][c0 + 8] = b;
  __syncthreads();
  u16x8 o0, o1;
#pragma unroll
  for (int j = 0; j < 8; ++j) o0[j] = sT[c0 + j][r];
#pragma unroll
  for (int j = 0; j < 8; ++j) o1[j] = sT[c0 + 8 + j][r];
  u16* dst = WT + (size_t)(n0 + r) * K + k0 + c0;
  *(u16x8*)dst = o0;
  *(u16x8*)(dst + 8) = o1;
}

// ---------------- LayerNorm (f32 in, bf16 out), one wave per row ----------
__global__ __launch_bounds__(256) void ln_kernel(const float* __restrict__ x,
                                                 const float* __restrict__ g,
                                                 const float* __restrict__ b,
                                                 u16* __restrict__ o) {
  int wid = threadIdx.x >> 6, lane = threadIdx.x & 63;
  long row = (long)blockIdx.x * 4 + wid;
  const float* xr = x + row * HID;
  float4 v0 = *(const float4*)(xr + lane * 8);
  float4 v1 = *(const float4*)(xr + lane * 8 + 4);
  float fr[8] = {v0.x, v0.y, v0.z, v0.w, v1.x, v1.y, v1.z, v1.w};
  float s = 0.f, q = 0.f;
#pragma unroll
  for (int j = 0; j < 8; ++j) { s += fr[j]; q += fr[j] * fr[j]; }
#pragma unroll
  for (int mby = 1; mby < 64; mby <<= 1) {
    s += __shfl_xor(s, mby);
    q += __shfl_xor(q, mby);
  }
  float mean = s * (1.f / HID);
  float var = q * (1.f / HID) - mean * mean;
  float rs = rsqrtf(var + 1e-5f);
  u16x8 ov;
#pragma unroll
  for (int j = 0; j < 8; ++j) {
    int c = lane * 8 + j;
    ov[j] = f2bf((fr[j] - mean) * rs * g[c] + b[c]);
  }
  *(u16x8*)(o + row * HID + lane * 8) = ov;
}

// ---------------- bf16 MFMA GEMM: C = A[MxK] * BT[NxK]^T  ------------------
// Tiles: BM x 64, BK=32; 4 waves (2x2); global_load_lds staging.
// EPI 0: fused QKV epilogue -> o1=q bf16 [r][512], o2=k bf16, o3=vt [b][h][d][s]
// EPI 1: o1 f32 = resid + acc + bias
// EPI 2: o1 bf16 = gelu(acc + bias)
template <int BM, int EPI>
__global__ __launch_bounds__(256) void gemm2_kernel(
    const u16* __restrict__ A, const u16* __restrict__ BT,
    const float* __restrict__ bias, const float* __restrict__ bias2,
    const float* __restrict__ bias3, const float* __restrict__ resid,
    void* __restrict__ o1, void* __restrict__ o2, void* __restrict__ o3,
    int M, int N, int K) {
  constexpr int AM = BM / 32;
  __shared__ alignas(16) u16 sA[BM * 32];
  __shared__ alignas(16) u16 sB[64 * 32];
  int tid = threadIdx.x, wid = tid >> 6, lane = tid & 63;
  int wm = wid >> 1, wn = wid & 1;
  int grp = lane >> 4, l16 = lane & 15;
  int m0 = blockIdx.y * BM, n0 = blockIdx.x * 64;
  f32x4 zz = {0.f, 0.f, 0.f, 0.f};
  f32x4 acc[AM][2];
#pragma unroll
  for (int i = 0; i < AM; ++i)
#pragma unroll
    for (int j = 0; j < 2; ++j) acc[i][j] = zz;

  for (int k0 = 0; k0 < K; k0 += 32) {
#pragma unroll
    for (int i = 0; i < BM / 64; ++i) {
      int boff = (wid * (BM / 64) + i) * 1024;
      int bb = boff + lane * 16;
      gl16((const char*)A + ((size_t)(m0 + (bb >> 6)) * K + k0) * 2 + (bb & 63),
           (char*)sA + boff);
    }
    {
      int boff = wid * 1024;
      int bb = boff + lane * 16;
      gl16((const char*)BT + ((size_t)(n0 + (bb >> 6)) * K + k0) * 2 + (bb & 63),
           (char*)sB + boff);
    }
    __syncthreads();
    bf16x8 af[AM], bfr[2];
#pragma unroll
    for (int am = 0; am < AM; ++am)
      af[am] = *(const bf16x8*)(sA + (wm * (BM / 2) + am * 16 + l16) * 32 + grp * 8);
#pragma unroll
    for (int bn = 0; bn < 2; ++bn)
      bfr[bn] = *(const bf16x8*)(sB + (wn * 32 + bn * 16 + l16) * 32 + grp * 8);
#pragma unroll
    for (int am = 0; am < AM; ++am)
#pragma unroll
      for (int bn = 0; bn < 2; ++bn)
        acc[am][bn] = __builtin_amdgcn_mfma_f32_16x16x32_bf16(af[am], bfr[bn],
                                                              acc[am][bn], 0, 0, 0);
    __syncthreads();
  }

#pragma unroll
  for (int am = 0; am < AM; ++am) {
#pragma unroll
    for (int bn = 0; bn < 2; ++bn) {
      int gc = n0 + wn * 32 + bn * 16 + l16;
      long gr0 = m0 + wm * (BM / 2) + am * 16 + grp * 4;
      if constexpr (EPI == 0) {
        if (gc < 1024) {
          u16* dst = (gc < 512) ? (u16*)o1 : (u16*)o2;
          int c = gc & 511;
          float bsv = (gc < 512) ? bias[c] : bias2[c];
#pragma unroll
          for (int r = 0; r < 4; ++r)
            dst[(size_t)(gr0 + r) * 512 + c] = f2bf(acc[am][bn][r] + bsv);
        } else {
          int c = gc - 1024;
          float bsv = bias3[c];
          int bidx = (int)(gr0 >> 11), s0 = (int)(gr0 & 2047);
          u16x4 pk;
#pragma unroll
          for (int r = 0; r < 4; ++r) pk[r] = f2bf(acc[am][bn][r] + bsv);
          *(u16x4*)((u16*)o3 +
                    ((size_t)(bidx * NHEAD + (c >> 6)) * DHEAD + (c & 63)) * S_LEN +
                    s0) = pk;
        }
      } else if constexpr (EPI == 1) {
        float bsv = bias[gc];
        float* O = (float*)o1;
#pragma unroll
        for (int r = 0; r < 4; ++r) {
          size_t off = (size_t)(gr0 + r) * N + gc;
          O[off] = resid[off] + acc[am][bn][r] + bsv;
        }
      } else {
        float bsv = bias[gc];
        u16* O = (u16*)o1;
#pragma unroll
        for (int r = 0; r < 4; ++r) {
          float v = acc[am][bn][r] + bsv;
          O[(size_t)(gr0 + r) * N + gc] =
              f2bf(0.5f * v * (1.f + erff(v * 0.70710678118f)));
        }
      }
    }
  }
}

// ---------------- flash attention, bf16 MFMA, online softmax ---------------
// V comes in transposed: vt[b][h][d][s]. No barriers (per-wave P, dbuf'd).
__global__ __launch_bounds__(256) void attn_kernel(
    const u16* __restrict__ qg, const u16* __restrict__ kg,
    const u16* __restrict__ vt, const unsigned char* __restrict__ mk,
    u16* __restrict__ og) {
  __shared__ alignas(16) u16 sP[2][4][16][72];
  int wid = threadIdx.x >> 6, lane = threadIdx.x & 63;
  int grp = lane >> 4, l16 = lane & 15;
  int h = blockIdx.y, b = blockIdx.z;
  int q0 = blockIdx.x * 64 + wid * 16;
  const u16* qp = qg + (size_t)(b * S_LEN + q0 + l16) * HID + h * DHEAD + grp * 8;
  bf16x8 qf0 = *(const bf16x8*)qp;
  bf16x8 qf1 = *(const bf16x8*)(qp + 32);
  f32x4 zz = {0.f, 0.f, 0.f, 0.f};
  f32x4 oa[4] = {zz, zz, zz, zz};
  float mrow[4] = {-1e30f, -1e30f, -1e30f, -1e30f};
  float lrow[4] = {0.f, 0.f, 0.f, 0.f};
  const unsigned char* mbase = mk + (size_t)b * S_LEN * S_LEN + (size_t)q0 * S_LEN;
  const u16* khead = kg + (size_t)b * S_LEN * HID + h * DHEAD;
  const u16* vhead = vt + (size_t)(b * NHEAD + h) * DHEAD * S_LEN;
  int buf = 0;
  for (int kv0 = 0; kv0 < S_LEN; kv0 += 64, buf ^= 1) {
    f32x4 sreg[4];
#pragma unroll
    for (int nb = 0; nb < 4; ++nb) {
      const u16* kp = khead + (size_t)(kv0 + nb * 16 + l16) * HID + grp * 8;
      bf16x8 kf0 = *(const bf16x8*)kp;
      bf16x8 kf1 = *(const bf16x8*)(kp + 32);
      f32x4 s = zz;
      s = __builtin_amdgcn_mfma_f32_16x16x32_bf16(qf0, kf0, s, 0, 0, 0);
      s = __builtin_amdgcn_mfma_f32_16x16x32_bf16(qf1, kf1, s, 0, 0, 0);
      sreg[nb] = s;
    }
#pragma unroll
    for (int r = 0; r < 4; ++r) {
      const unsigned char* mp = mbase + (size_t)(grp * 4 + r) * S_LEN + kv0;
      float sv[4];
      float mx = -1e30f;
#pragma unroll
      for (int nb = 0; nb < 4; ++nb) {
        sv[nb] = mp[nb * 16 + l16] ? sreg[nb][r] * 0.125f : -1e9f;
        mx = fmaxf(mx, sv[nb]);
      }
      mx = fmaxf(mx, __shfl_xor(mx, 1));
      mx = fmaxf(mx, __shfl_xor(mx, 2));
      mx = fmaxf(mx, __shfl_xor(mx, 4));
      mx = fmaxf(mx, __shfl_xor(mx, 8));
      float mnew = fmaxf(mrow[r], mx);
      float scale = __expf(mrow[r] - mnew);
      float rsum = 0.f;
#pragma unroll
      for (int nb = 0; nb < 4; ++nb) {
        float p = __expf(sv[nb] - mnew);
        rsum += p;
        sP[buf][wid][grp * 4 + r][nb * 16 + l16] = f2bf(p);
      }
      rsum += __shfl_xor(rsum, 1);
      rsum += __shfl_xor(rsum, 2);
      rsum += __shfl_xor(rsum, 4);
      rsum += __shfl_xor(rsum, 8);
      mrow[r] = mnew;
      lrow[r] = lrow[r] * scale + rsum;
#pragma unroll
      for (int db = 0; db < 4; ++db) oa[db][r] *= scale;
    }
    // per-wave LDS visibility: wait for our own sP writes (no block barrier)
    asm volatile("s_waitcnt lgkmcnt(0)" ::: "memory");
#pragma unroll
    for (int ks = 0; ks < 2; ++ks) {
      bf16x8 pa = *(const bf16x8*)&sP[buf][wid][l16][ks * 32 + grp * 8];
#pragma unroll
      for (int db = 0; db < 4; ++db) {
        bf16x8 vf = *(const bf16x8*)(vhead + (size_t)(db * 16 + l16) * S_LEN +
                                     kv0 + ks * 32 + grp * 8);
        oa[db] = __builtin_amdgcn_mfma_f32_16x16x32_bf16(pa, vf, oa[db], 0, 0, 0);
      }
    }
  }
#pragma unroll
  for (int r = 0; r < 4; ++r) {
    float inv = 1.f / lrow[r];
    size_t orow = (size_t)b * S_LEN + q0 + grp * 4 + r;
#pragma unroll
    for (int db = 0; db < 4; ++db)
      og[orow * HID + h * DHEAD + db * 16 + l16] = f2bf(oa[db][r] * inv);
  }
}

// ---------------- launch ----------------
extern "C" void kernel_launch(void* const* d_in, const int* in_sizes, int n_in,
                              void* d_out, int out_size, void* d_ws,
                              size_t ws_size, hipStream_t stream) {
  const float* x = (const float*)d_in[0];
  const void* mask = d_in[1];
  const float* ln1g = (const float*)d_in[2];
  const float* ln1b = (const float*)d_in[3];
  const float* ln2g = (const float*)d_in[4];
  const float* ln2b = (const float*)d_in[5];
  const float* Wq = (const float*)d_in[6];
  const float* bq = (const float*)d_in[7];
  const float* Wk = (const float*)d_in[8];
  const float* bk = (const float*)d_in[9];
  const float* Wv = (const float*)d_in[10];
  const float* bvp = (const float*)d_in[11];
  const float* Wo = (const float*)d_in[12];
  const float* bo = (const float*)d_in[13];
  const float* W1 = (const float*)d_in[14];
  const float* b1 = (const float*)d_in[15];
  const float* W2 = (const float*)d_in[16];
  const float* b2 = (const float*)d_in[17];

  char* w = (char*)d_ws;
  int* flag = (int*)w;
  char* base = w + 256;
  // layout (same 44 MB footprint as round 1):
  //  [0 .. 16.78M): mcan(8.39M) | nx(4.19M) | q(4.19M)   -> later hb(16.78M)
  //  k(4.19M -> later nx2) | vt(4.19M) | ao(4.19M) | x2(8.39M) | weights(6.29M)
  unsigned char* mcan = (unsigned char*)base;
  u16* nx = (u16*)(base + 8388608);
  u16* qb = (u16*)(base + 12582912);
  u16* hb = (u16*)base;
  u16* kb = (u16*)(base + 16777216);
  u16* nx2 = kb;
  u16* vtb = (u16*)(base + 20971520);
  u16* aob = (u16*)(base + 25165824);
  float* x2 = (float*)(base + 29360128);
  u16* wqkvT = (u16*)(base + 37748736);       // 1536 x 512
  u16* woT = wqkvT + 1536 * 512;              // 512 x 512
  u16* w1T = woT + 512 * 512;                 // 2048 x 512
  u16* w2T = w1T + 2048 * 512;                // 512 x 2048

  detect_mask_kernel<<<1, 64, 0, stream>>>((const unsigned int*)mask, flag);
  mask_canon_kernel<<<4096, 256, 0, stream>>>(mask, flag, mcan,
                                              BATCH * S_LEN * S_LEN);
  cvt_t_kernel<<<dim3(8, 8), 256, 0, stream>>>(Wq, wqkvT, 512, 512);
  cvt_t_kernel<<<dim3(8, 8), 256, 0, stream>>>(Wk, wqkvT + 512 * 512, 512, 512);
  cvt_t_kernel<<<dim3(8, 8), 256, 0, stream>>>(Wv, wqkvT + 1024 * 512, 512, 512);
  cvt_t_kernel<<<dim3(8, 8), 256, 0, stream>>>(Wo, woT, 512, 512);
  cvt_t_kernel<<<dim3(32, 8), 256, 0, stream>>>(W1, w1T, 512, 2048);
  cvt_t_kernel<<<dim3(8, 32), 256, 0, stream>>>(W2, w2T, 2048, 512);
  ln_kernel<<<1024, 256, 0, stream>>>(x, ln1g, ln1b, nx);
  // fused QKV: N = 1536, writes q, k, vt
  gemm2_kernel<128, 0><<<dim3(24, 32), 256, 0, stream>>>(
      nx, wqkvT, bq, bk, bvp, nullptr, qb, kb, vtb, ROWS, 1536, HID);
  attn_kernel<<<dim3(32, 8, 2), 256, 0, stream>>>(qb, kb, vtb, mcan, aob);
  // O-proj + residual -> x2 (f32)
  gemm2_kernel<64, 1><<<dim3(8, 64), 256, 0, stream>>>(
      aob, woT, bo, nullptr, nullptr, x, x2, nullptr, nullptr, ROWS, 512, 512);
  ln_kernel<<<1024, 256, 0, stream>>>(x2, ln2g, ln2b, nx2);
  // FFN1 + gelu -> hb
  gemm2_kernel<128, 2><<<dim3(32, 32), 256, 0, stream>>>(
      nx2, w1T, b1, nullptr, nullptr, nullptr, hb, nullptr, nullptr, ROWS, DFF, HID);
  // FFN2 + residual -> out (f32)
  gemm2_kernel<64, 1><<<dim3(8, 64), 256, 0, stream>>>(
      hb, w2T, b2, nullptr, nullptr, x2, d_out, nullptr, nullptr, ROWS, 512, DFF);
}

// Round 3
// 233.269 us; speedup vs baseline: 1.4874x; 1.1279x over previous
//
#include <hip/hip_runtime.h>
#include <math.h>

typedef unsigned short u16;
typedef unsigned long long u64;
typedef __bf16 bf16x8 __attribute__((ext_vector_type(8)));
typedef float f32x4 __attribute__((ext_vector_type(4)));
typedef unsigned short u16x8 __attribute__((ext_vector_type(8)));
typedef unsigned short u16x4 __attribute__((ext_vector_type(4)));

#define S_LEN 2048
#define BATCH 2
#define HID 512
#define NHEAD 8
#define DHEAD 64
#define DFF 2048
#define ROWS (BATCH * S_LEN)  // 4096

static __device__ __forceinline__ u16 f2bf(float f) {
  unsigned int u = __builtin_bit_cast(unsigned int, f);
  u += 0x7fffu + ((u >> 16) & 1u);
  return (u16)(u >> 16);
}

// async global->LDS, 16B per lane; lds dest is wave-uniform base (+lane*16 by HW).
static __device__ __forceinline__ void gl16(const void* g, void* l) {
  __builtin_amdgcn_global_load_lds(
      (const __attribute__((address_space(1))) void*)g,
      (__attribute__((address_space(3))) void*)l, 16, 0, 0);
}

// ---------------- mask dtype detection ----------------
__global__ void detect_mask_kernel(const unsigned int* __restrict__ m,
                                   int* __restrict__ flag) {
  int lane = threadIdx.x & 63;
  int notint = 0, notf32 = 0;
  for (int i = lane; i < 1024; i += 64) {
    unsigned int v = m[i];
    if (v > 1u) notint = 1;
    if (v != 0u && v != 0x3f800000u) notf32 = 1;
  }
  unsigned long long bi = __ballot(notint);
  unsigned long long bf = __ballot(notf32);
  if (lane == 0) *flag = (bi == 0ull) ? 1 : ((bf == 0ull) ? 2 : 0);
}

// ---------------- mask -> bit-packed uint64 (one word per row per 64 cols) --
__global__ __launch_bounds__(256) void mask_pack_kernel(
    const void* __restrict__ m, const int* __restrict__ flagp,
    u64* __restrict__ out) {
  int flag = *flagp;
  int lane = threadIdx.x & 63;
  int gw = (blockIdx.x * 256 + threadIdx.x) >> 6;
  int nw = (gridDim.x * 256) >> 6;
  const int nwords = ROWS * (S_LEN / 64);  // 131072
  for (int wI = gw; wI < nwords; wI += nw) {
    size_t e = (size_t)wI * 64 + lane;
    bool bit;
    if (flag == 1) bit = ((const int*)m)[e] != 0;
    else if (flag == 2) bit = ((const float*)m)[e] != 0.f;
    else bit = ((const unsigned char*)m)[e] != 0;
    u64 bb = __ballot(bit);
    if (lane == 0) out[wI] = bb;
  }
}

// ---------------- f32 W[K][N] -> bf16 WT[N][K] tiled transpose-convert ----
__global__ __launch_bounds__(256) void cvt_t_kernel(const float* __restrict__ W,
                                                    u16* __restrict__ WT,
                                                    int K, int N) {
  __shared__ u16 sT[64][80];
  int tid = threadIdx.x;
  int r = tid >> 2, c0 = (tid & 3) * 16;
  int k0 = blockIdx.y * 64, n0 = blockIdx.x * 64;
  const float* src = W + (size_t)(k0 + r) * N + n0 + c0;
  u16x8 a, b;
#pragma unroll
  for (int j = 0; j < 8; ++j) a[j] = f2bf(src[j]);
#pragma unroll
  for (int j = 0; j < 8; ++j) b[j] = f2bf(src[8 + j]);
  *(u16x8*)&sT[r][c0] = a;
  *(u16x8*)&sT[r][c0 + 8] = b;
  __syncthreads();
  u16x8 o0, o1;
#pragma unroll
  for (int j = 0; j < 8; ++j) o0[j] = sT[c0 + j][r];
#pragma unroll
  for (int j = 0; j < 8; ++j) o1[j] = sT[c0 + 8 + j][r];
  u16* dst = WT + (size_t)(n0 + r) * K + k0 + c0;
  *(u16x8*)dst = o0;
  *(u16x8*)(dst + 8) = o1;
}

// ---------------- LayerNorm (f32 in, bf16 out), one wave per row ----------
__global__ __launch_bounds__(256) void ln_kernel(const float* __restrict__ x,
                                                 const float* __restrict__ g,
                                                 const float* __restrict__ b,
                                                 u16* __restrict__ o) {
  int wid = threadIdx.x >> 6, lane = threadIdx.x & 63;
  long row = (long)blockIdx.x * 4 + wid;
  const float* xr = x + row * HID;
  float4 v0 = *(const float4*)(xr + lane * 8);
  float4 v1 = *(const float4*)(xr + lane * 8 + 4);
  float fr[8] = {v0.x, v0.y, v0.z, v0.w, v1.x, v1.y, v1.z, v1.w};
  float s = 0.f, q = 0.f;
#pragma unroll
  for (int j = 0; j < 8; ++j) { s += fr[j]; q += fr[j] * fr[j]; }
#pragma unroll
  for (int mby = 1; mby < 64; mby <<= 1) {
    s += __shfl_xor(s, mby);
    q += __shfl_xor(q, mby);
  }
  float mean = s * (1.f / HID);
  float var = q * (1.f / HID) - mean * mean;
  float rs = rsqrtf(var + 1e-5f);
  u16x8 ov;
#pragma unroll
  for (int j = 0; j < 8; ++j) {
    int c = lane * 8 + j;
    ov[j] = f2bf((fr[j] - mean) * rs * g[c] + b[c]);
  }
  *(u16x8*)(o + row * HID + lane * 8) = ov;
}

// ---------------- bf16 MFMA GEMM: C = A[MxK] * BT[NxK]^T, BK=64 ------------
// LDS tiles in [row][128B] with st-16x32-style XOR swizzle (byte ^= (row&7)<<4)
// applied on the GLOBAL source (gl_lds writes linearly) and on ds_read addrs.
// EPI 0: fused QKV -> o1=q bf16 [r][512], o2=k bf16, o3=vt [b][h][d][s]
// EPI 1: o1 f32 = resid + acc + bias
// EPI 2: o1 bf16 = gelu(acc + bias)
template <int BM, int EPI>
__global__ __launch_bounds__(256) void gemm2_kernel(
    const u16* __restrict__ A, const u16* __restrict__ BT,
    const float* __restrict__ bias, const float* __restrict__ bias2,
    const float* __restrict__ bias3, const float* __restrict__ resid,
    void* __restrict__ o1, void* __restrict__ o2, void* __restrict__ o3,
    int M, int N, int K) {
  constexpr int AM = BM / 32;
  __shared__ alignas(16) u16 sA[BM * 64];
  __shared__ alignas(16) u16 sB[64 * 64];
  int tid = threadIdx.x, wid = tid >> 6, lane = tid & 63;
  int wm = wid >> 1, wn = wid & 1;
  int grp = lane >> 4, l16 = lane & 15;
  int m0 = blockIdx.y * BM, n0 = blockIdx.x * 64;
  f32x4 zz = {0.f, 0.f, 0.f, 0.f};
  f32x4 acc[AM][2];
#pragma unroll
  for (int i = 0; i < AM; ++i)
#pragma unroll
    for (int j = 0; j < 2; ++j) acc[i][j] = zz;

  for (int k0 = 0; k0 < K; k0 += 64) {
#pragma unroll
    for (int i = 0; i < BM / 32; ++i) {
      int bb = i * 4096 + tid * 16;
      int row = bb >> 7;
      int cb = (bb & 127) ^ ((row & 7) << 4);
      gl16((const char*)A + ((size_t)(m0 + row) * K + k0) * 2 + cb,
           (char*)sA + i * 4096 + wid * 1024);
    }
#pragma unroll
    for (int i = 0; i < 2; ++i) {
      int bb = i * 4096 + tid * 16;
      int row = bb >> 7;
      int cb = (bb & 127) ^ ((row & 7) << 4);
      gl16((const char*)BT + ((size_t)(n0 + row) * K + k0) * 2 + cb,
           (char*)sB + i * 4096 + wid * 1024);
    }
    __syncthreads();
    bf16x8 af[AM][2], bfr[2][2];
#pragma unroll
    for (int am = 0; am < AM; ++am) {
      int row = wm * (BM / 2) + am * 16 + l16;
#pragma unroll
      for (int kk = 0; kk < 2; ++kk)
        af[am][kk] = *(const bf16x8*)((const char*)sA + row * 128 +
                                      ((kk * 64 + grp * 16) ^ ((row & 7) << 4)));
    }
#pragma unroll
    for (int bn = 0; bn < 2; ++bn) {
      int row = wn * 32 + bn * 16 + l16;
#pragma unroll
      for (int kk = 0; kk < 2; ++kk)
        bfr[bn][kk] = *(const bf16x8*)((const char*)sB + row * 128 +
                                       ((kk * 64 + grp * 16) ^ ((row & 7) << 4)));
    }
#pragma unroll
    for (int kk = 0; kk < 2; ++kk)
#pragma unroll
      for (int am = 0; am < AM; ++am)
#pragma unroll
        for (int bn = 0; bn < 2; ++bn)
          acc[am][bn] = __builtin_amdgcn_mfma_f32_16x16x32_bf16(
              af[am][kk], bfr[bn][kk], acc[am][bn], 0, 0, 0);
    __syncthreads();
  }

#pragma unroll
  for (int am = 0; am < AM; ++am) {
#pragma unroll
    for (int bn = 0; bn < 2; ++bn) {
      int gc = n0 + wn * 32 + bn * 16 + l16;
      long gr0 = m0 + wm * (BM / 2) + am * 16 + grp * 4;
      if constexpr (EPI == 0) {
        if (gc < 1024) {
          u16* dst = (gc < 512) ? (u16*)o1 : (u16*)o2;
          int c = gc & 511;
          float bsv = (gc < 512) ? bias[c] : bias2[c];
#pragma unroll
          for (int r = 0; r < 4; ++r)
            dst[(size_t)(gr0 + r) * 512 + c] = f2bf(acc[am][bn][r] + bsv);
        } else {
          int c = gc - 1024;
          float bsv = bias3[c];
          int bidx = (int)(gr0 >> 11), s0 = (int)(gr0 & 2047);
          u16x4 pk;
#pragma unroll
          for (int r = 0; r < 4; ++r) pk[r] = f2bf(acc[am][bn][r] + bsv);
          *(u16x4*)((u16*)o3 +
                    ((size_t)(bidx * NHEAD + (c >> 6)) * DHEAD + (c & 63)) * S_LEN +
                    s0) = pk;
        }
      } else if constexpr (EPI == 1) {
        float bsv = bias[gc];
        float* O = (float*)o1;
#pragma unroll
        for (int r = 0; r < 4; ++r) {
          size_t off = (size_t)(gr0 + r) * N + gc;
          O[off] = resid[off] + acc[am][bn][r] + bsv;
        }
      } else {
        float bsv = bias[gc];
        u16* O = (u16*)o1;
#pragma unroll
        for (int r = 0; r < 4; ++r) {
          float v = acc[am][bn][r] + bsv;
          O[(size_t)(gr0 + r) * N + gc] =
              f2bf(0.5f * v * (1.f + erff(v * 0.70710678118f)));
        }
      }
    }
  }
}

// ---------------- flash attention: swapped QK^T and PV (lane-local softmax) -
// Per wave: 16 q-rows (q = l16). st = mfma(K,Q) -> lane holds S^T[k][q=l16];
// softmax reduce = in-register tree + shfl_xor(16,32); P via LDS relayout;
// O^T = mfma(V^T, P): col=q=l16 so rescale/div are lane-local. No barriers.
__global__ __launch_bounds__(256) void attn_kernel(
    const u16* __restrict__ qg, const u16* __restrict__ kg,
    const u16* __restrict__ vt, const u64* __restrict__ mpk,
    u16* __restrict__ og) {
  __shared__ alignas(16) u16 sP[2][4][16][72];
  int wid = threadIdx.x >> 6, lane = threadIdx.x & 63;
  int grp = lane >> 4, l16 = lane & 15;
  // XCD swizzle: 512 blocks -> 64-block contiguous chunk per XCD (2 heads/XCD)
  int flat = blockIdx.x;
  int swz = (flat & 7) * 64 + (flat >> 3);
  int b = swz >> 8;
  int h = (swz >> 5) & 7;
  int q0 = (swz & 31) * 64 + wid * 16;
  int q = q0 + l16;
  const u16* qp = qg + (size_t)(b * S_LEN + q) * HID + h * DHEAD + grp * 8;
  bf16x8 qf0 = *(const bf16x8*)qp;
  bf16x8 qf1 = *(const bf16x8*)(qp + 32);
  f32x4 zz = {0.f, 0.f, 0.f, 0.f};
  f32x4 oa[4] = {zz, zz, zz, zz};
  float mr = -1e30f, lr = 0.f;
  const u64* mrowp = mpk + (size_t)(b * S_LEN + q) * (S_LEN / 64);
  const u16* khead = kg + (size_t)b * S_LEN * HID + h * DHEAD;
  const u16* vhead = vt + (size_t)(b * NHEAD + h) * DHEAD * S_LEN;
  int buf = 0;
  for (int kv0 = 0; kv0 < S_LEN; kv0 += 64, buf ^= 1) {
    f32x4 st[4];
#pragma unroll
    for (int nb = 0; nb < 4; ++nb) {
      const u16* kp = khead + (size_t)(kv0 + nb * 16 + l16) * HID + grp * 8;
      bf16x8 kf0 = *(const bf16x8*)kp;
      bf16x8 kf1 = *(const bf16x8*)(kp + 32);
      f32x4 s = zz;
      s = __builtin_amdgcn_mfma_f32_16x16x32_bf16(kf0, qf0, s, 0, 0, 0);
      s = __builtin_amdgcn_mfma_f32_16x16x32_bf16(kf1, qf1, s, 0, 0, 0);
      st[nb] = s;
    }
    u64 mw = mrowp[kv0 >> 6];
    float sv[16];
    float tmx = -1e30f;
#pragma unroll
    for (int nb = 0; nb < 4; ++nb)
#pragma unroll
      for (int r = 0; r < 4; ++r) {
        int kb = nb * 16 + grp * 4 + r;
        float s = st[nb][r] * 0.125f;
        sv[nb * 4 + r] = ((mw >> kb) & 1ull) ? s : -1e9f;
        tmx = fmaxf(tmx, sv[nb * 4 + r]);
      }
    tmx = fmaxf(tmx, __shfl_xor(tmx, 16));
    tmx = fmaxf(tmx, __shfl_xor(tmx, 32));
    float mnew = fmaxf(mr, tmx);
    float sc = __expf(mr - mnew);
    float tsum = 0.f;
    u16x4 pk0, pk1, pk2, pk3;
#pragma unroll
    for (int r = 0; r < 4; ++r) {
      float p0 = __expf(sv[0 + r] - mnew);
      float p1 = __expf(sv[4 + r] - mnew);
      float p2 = __expf(sv[8 + r] - mnew);
      float p3 = __expf(sv[12 + r] - mnew);
      tsum += p0 + p1 + p2 + p3;
      pk0[r] = f2bf(p0); pk1[r] = f2bf(p1); pk2[r] = f2bf(p2); pk3[r] = f2bf(p3);
    }
    *(u16x4*)&sP[buf][wid][l16][0 + grp * 4] = pk0;
    *(u16x4*)&sP[buf][wid][l16][16 + grp * 4] = pk1;
    *(u16x4*)&sP[buf][wid][l16][32 + grp * 4] = pk2;
    *(u16x4*)&sP[buf][wid][l16][48 + grp * 4] = pk3;
    tsum += __shfl_xor(tsum, 16);
    tsum += __shfl_xor(tsum, 32);
    mr = mnew;
    lr = lr * sc + tsum;
#pragma unroll
    for (int db = 0; db < 4; ++db)
#pragma unroll
      for (int r = 0; r < 4; ++r) oa[db][r] *= sc;
    asm volatile("s_waitcnt lgkmcnt(0)" ::: "memory");
#pragma unroll
    for (int ks = 0; ks < 2; ++ks) {
      bf16x8 pb = *(const bf16x8*)&sP[buf][wid][l16][ks * 32 + grp * 8];
#pragma unroll
      for (int db = 0; db < 4; ++db) {
        bf16x8 vf = *(const bf16x8*)(vhead + (size_t)(db * 16 + l16) * S_LEN +
                                     kv0 + ks * 32 + grp * 8);
        oa[db] = __builtin_amdgcn_mfma_f32_16x16x32_bf16(vf, pb, oa[db], 0, 0, 0);
      }
    }
  }
  // epilogue: O^T -> [q][d] via LDS, then coalesced b128 stores
  float inv = 1.f / lr;
#pragma unroll
  for (int db = 0; db < 4; ++db) {
    u16x4 pk;
#pragma unroll
    for (int r = 0; r < 4; ++r) pk[r] = f2bf(oa[db][r] * inv);
    *(u16x4*)&sP[0][wid][l16][db * 16 + grp * 4] = pk;
  }
  asm volatile("s_waitcnt lgkmcnt(0)" ::: "memory");
  u16x8 o0 = *(const u16x8*)&sP[0][wid][l16][grp * 16];
  u16x8 o1 = *(const u16x8*)&sP[0][wid][l16][grp * 16 + 8];
  u16* op = og + (size_t)(b * S_LEN + q) * HID + h * DHEAD + grp * 16;
  *(u16x8*)op = o0;
  *(u16x8*)(op + 8) = o1;
}

// ---------------- launch ----------------
extern "C" void kernel_launch(void* const* d_in, const int* in_sizes, int n_in,
                              void* d_out, int out_size, void* d_ws,
                              size_t ws_size, hipStream_t stream) {
  const float* x = (const float*)d_in[0];
  const void* mask = d_in[1];
  const float* ln1g = (const float*)d_in[2];
  const float* ln1b = (const float*)d_in[3];
  const float* ln2g = (const float*)d_in[4];
  const float* ln2b = (const float*)d_in[5];
  const float* Wq = (const float*)d_in[6];
  const float* bq = (const float*)d_in[7];
  const float* Wk = (const float*)d_in[8];
  const float* bk = (const float*)d_in[9];
  const float* Wv = (const float*)d_in[10];
  const float* bvp = (const float*)d_in[11];
  const float* Wo = (const float*)d_in[12];
  const float* bo = (const float*)d_in[13];
  const float* W1 = (const float*)d_in[14];
  const float* b1 = (const float*)d_in[15];
  const float* W2 = (const float*)d_in[16];
  const float* b2 = (const float*)d_in[17];

  char* w = (char*)d_ws;
  int* flag = (int*)w;
  char* base = w + 256;
  // layout:
  //  [0 .. 16.78M): mpk(1M) | nx(@8.39M) | q(@12.58M)  -> later hb(16.78M)
  //  k(@16.78M -> later nx2) | vt(@20.97M) | ao(@25.17M) | x2(@29.36M f32)
  //  bf16 weights @37.75M
  u64* mpk = (u64*)base;
  u16* nx = (u16*)(base + 8388608);
  u16* qb = (u16*)(base + 12582912);
  u16* hb = (u16*)base;
  u16* kb = (u16*)(base + 16777216);
  u16* nx2 = kb;
  u16* vtb = (u16*)(base + 20971520);
  u16* aob = (u16*)(base + 25165824);
  float* x2 = (float*)(base + 29360128);
  u16* wqkvT = (u16*)(base + 37748736);  // 1536 x 512
  u16* woT = wqkvT + 1536 * 512;         // 512 x 512
  u16* w1T = woT + 512 * 512;            // 2048 x 512
  u16* w2T = w1T + 2048 * 512;           // 512 x 2048

  detect_mask_kernel<<<1, 64, 0, stream>>>((const unsigned int*)mask, flag);
  mask_pack_kernel<<<2048, 256, 0, stream>>>(mask, flag, mpk);
  cvt_t_kernel<<<dim3(8, 8), 256, 0, stream>>>(Wq, wqkvT, 512, 512);
  cvt_t_kernel<<<dim3(8, 8), 256, 0, stream>>>(Wk, wqkvT + 512 * 512, 512, 512);
  cvt_t_kernel<<<dim3(8, 8), 256, 0, stream>>>(Wv, wqkvT + 1024 * 512, 512, 512);
  cvt_t_kernel<<<dim3(8, 8), 256, 0, stream>>>(Wo, woT, 512, 512);
  cvt_t_kernel<<<dim3(32, 8), 256, 0, stream>>>(W1, w1T, 512, 2048);
  cvt_t_kernel<<<dim3(8, 32), 256, 0, stream>>>(W2, w2T, 2048, 512);
  ln_kernel<<<1024, 256, 0, stream>>>(x, ln1g, ln1b, nx);
  // fused QKV: N = 1536, writes q, k, vt
  gemm2_kernel<128, 0><<<dim3(24, 32), 256, 0, stream>>>(
      nx, wqkvT, bq, bk, bvp, nullptr, qb, kb, vtb, ROWS, 1536, HID);
  attn_kernel<<<512, 256, 0, stream>>>(qb, kb, vtb, mpk, aob);
  // O-proj + residual -> x2 (f32)
  gemm2_kernel<64, 1><<<dim3(8, 64), 256, 0, stream>>>(
      aob, woT, bo, nullptr, nullptr, x, x2, nullptr, nullptr, ROWS, 512, 512);
  ln_kernel<<<1024, 256, 0, stream>>>(x2, ln2g, ln2b, nx2);
  // FFN1 + gelu -> hb
  gemm2_kernel<128, 2><<<dim3(32, 32), 256, 0, stream>>>(
      nx2, w1T, b1, nullptr, nullptr, nullptr, hb, nullptr, nullptr, ROWS, DFF,
      HID);
  // FFN2 + residual -> out (f32)
  gemm2_kernel<64, 1><<<dim3(8, 64), 256, 0, stream>>>(
      hb, w2T, b2, nullptr, nullptr, x2, d_out, nullptr, nullptr, ROWS, 512,
      DFF);
}